// Round 2
// baseline (5390.945 us; speedup 1.0000x reference)
//
#include <hip/hip_runtime.h>
#include <cstdint>

// TGN memory update: message scatter-mean + GRU cell.
// Decomposition: aggr = [mem_self | ACC/cnt] where ACC = sum over incident
// messages of [mem_other | raw | tenc]; gi = W1*mem + W234*(ACC/cnt) (only if
// cnt>0 else b_ih), gh = W_hh*mem; GRU fused in phase 2.

#define MEMD 128
#define ACCD 384

// ---------------- Phase 1: per-event scatter ----------------
__global__ __launch_bounds__(256) void tgn_scatter(
    const float* __restrict__ memory, const int* __restrict__ last_update,
    const int* __restrict__ src, const int* __restrict__ dst, const int* __restrict__ t,
    const float* __restrict__ raw_msg, const float* __restrict__ time_w,
    const float* __restrict__ time_b,
    float* __restrict__ ACC, int* __restrict__ cnt, int* __restrict__ lu_new,
    int n_events)
{
    const int e = blockIdx.x * 2 + (threadIdx.x >> 7);
    if (e >= n_events) return;
    const int j = threadIdx.x & 127;

    const int s = src[e];
    const int d = dst[e];
    const int te = t[e];

    const float tw = time_w[j];
    const float tb = time_b[j];
    const float dts = (float)(te - last_update[s]);
    const float dtd = (float)(te - last_update[d]);
    const float tenc_s = __cosf(fmaf(dts, tw, tb));
    const float tenc_d = __cosf(fmaf(dtd, tw, tb));

    const float ms = memory[(size_t)s * MEMD + j];
    const float md = memory[(size_t)d * MEMD + j];
    const float rw = raw_msg[(size_t)e * MEMD + j];

    float* As = ACC + (size_t)s * ACCD;
    float* Ad = ACC + (size_t)d * ACCD;
    // message aggregated at s: [mem_d | raw | tenc(t - lu[s])]
    atomicAdd(As + j, md);
    atomicAdd(As + 128 + j, rw);
    atomicAdd(As + 256 + j, tenc_s);
    // message aggregated at d: [mem_s | raw | tenc(t - lu[d])]
    atomicAdd(Ad + j, ms);
    atomicAdd(Ad + 128 + j, rw);
    atomicAdd(Ad + 256 + j, tenc_d);

    if (j == 0) {
        atomicAdd(cnt + s, 1);
        atomicAdd(cnt + d, 1);
        atomicMax(lu_new + s, te);
        atomicMax(lu_new + d, te);
    }
}

// ---------------- Phase 2: fused GEMM + GRU ----------------
// Block: 512 threads (8 waves), tile of 64 nodes.
// X row per node (512 f32): [mem (128) | ACC/max(cnt,1) (384)]
// LDS layout X[kc][m]: float4 chunk kc (k=4*kc) of node m -> conflict-free
// ds_read_b128 (consecutive lanes = consecutive 16B).
#define DOT4(acc_, Wp_, kk_, xv_)                       \
    acc_ = fmaf((xv_).x, (Wp_)[(kk_) + 0], acc_);       \
    acc_ = fmaf((xv_).y, (Wp_)[(kk_) + 1], acc_);       \
    acc_ = fmaf((xv_).z, (Wp_)[(kk_) + 2], acc_);       \
    acc_ = fmaf((xv_).w, (Wp_)[(kk_) + 3], acc_);

__global__ __launch_bounds__(512) void tgn_gru(
    const float* __restrict__ memory, const float* __restrict__ ACC,
    const int* __restrict__ cnt,
    const float* __restrict__ W_ih, const float* __restrict__ W_hh,
    const float* __restrict__ b_ih, const float* __restrict__ b_hh,
    float* __restrict__ out, int n_nodes)
{
    __shared__ float4 X[128][64]; // 128 KB

    const int tid = threadIdx.x;
    const int node0 = blockIdx.x * 64;

    // ---- stage tile ----
    for (int idx = tid; idx < 64 * 128; idx += 512) {
        const int m = idx >> 7;       // node in tile
        const int kc = idx & 127;     // float4 chunk
        int node = node0 + m;
        if (node >= n_nodes) node = n_nodes - 1; // clamp (harmless dup reads)
        float4 v;
        if (kc < 32) {
            v = *reinterpret_cast<const float4*>(memory + (size_t)node * MEMD + kc * 4);
        } else {
            const int c = cnt[node];
            const float inv = (c > 0) ? (1.0f / (float)c) : 0.0f;
            float4 a = *reinterpret_cast<const float4*>(ACC + (size_t)node * ACCD + (kc - 32) * 4);
            v = make_float4(a.x * inv, a.y * inv, a.z * inv, a.w * inv);
        }
        X[kc][m] = v;
    }
    __syncthreads();

    const int lane = tid & 63;  // node within tile
    const int wv = __builtin_amdgcn_readfirstlane(tid >> 6); // wave id 0..7 (uniform)
    const int node = node0 + lane;
    if (node >= n_nodes) return;

    const bool has = (cnt[node] > 0);

    for (int jj = 0; jj < 16; ++jj) {
        const int j = wv * 16 + jj;  // uniform per wave -> scalar weight loads

        const float* wir = W_ih + (size_t)j * 512;
        const float* wiz = wir + 128 * 512;
        const float* win = wir + 256 * 512;
        const float* whr = W_hh + (size_t)j * 128;
        const float* whz = whr + 128 * 128;
        const float* whn = whr + 256 * 128;

        float air = 0.f, aiz = 0.f, ain = 0.f;
        float ahr = 0.f, ahz = 0.f, ahn = 0.f;

        // k in [0,128): mem part -> feeds both W1 (i) and W_hh (h)
        #pragma unroll 8
        for (int kc = 0; kc < 32; ++kc) {
            const float4 xv = X[kc][lane];
            const int k = kc * 4;
            DOT4(air, wir, k, xv)
            DOT4(aiz, wiz, k, xv)
            DOT4(ain, win, k, xv)
            DOT4(ahr, whr, k, xv)
            DOT4(ahz, whz, k, xv)
            DOT4(ahn, whn, k, xv)
        }
        // k in [128,512): aggregated message part -> i gates only
        #pragma unroll 8
        for (int kc = 32; kc < 128; ++kc) {
            const float4 xv = X[kc][lane];
            const int k = kc * 4;
            DOT4(air, wir, k, xv)
            DOT4(aiz, wiz, k, xv)
            DOT4(ain, win, k, xv)
        }

        const float gir = (has ? air : 0.f) + b_ih[j];
        const float giz = (has ? aiz : 0.f) + b_ih[j + 128];
        const float gin = (has ? ain : 0.f) + b_ih[j + 256];
        const float ghr = ahr + b_hh[j];
        const float ghz = ahz + b_hh[j + 128];
        const float ghn = ahn + b_hh[j + 256];

        const float r = 1.0f / (1.0f + __expf(-(gir + ghr)));
        const float z = 1.0f / (1.0f + __expf(-(giz + ghz)));
        const float n = tanhf(fmaf(r, ghn, gin));

        const float4 xm = X[j >> 2][lane];
        const int sel = j & 3; // uniform per wave
        const float memj = (sel == 0) ? xm.x : (sel == 1) ? xm.y : (sel == 2) ? xm.z : xm.w;

        out[(size_t)node * MEMD + j] = (1.0f - z) * n + z * memj;
    }
}

// ---------------- Phase 3: last_update -> float out ----------------
__global__ void tgn_lu_out(const int* __restrict__ lu, float* __restrict__ out2, int n_nodes)
{
    const int i = blockIdx.x * blockDim.x + threadIdx.x;
    if (i < n_nodes) out2[i] = (float)lu[i];
}

extern "C" void kernel_launch(void* const* d_in, const int* in_sizes, int n_in,
                              void* d_out, int out_size, void* d_ws, size_t ws_size,
                              hipStream_t stream)
{
    const float* memory      = (const float*)d_in[0];
    const int*   last_update = (const int*)d_in[1];
    const int*   src         = (const int*)d_in[2];
    const int*   dst         = (const int*)d_in[3];
    const int*   t           = (const int*)d_in[4];
    const float* raw_msg     = (const float*)d_in[5];
    const float* time_w      = (const float*)d_in[6];
    const float* time_b      = (const float*)d_in[7];
    const float* W_ih        = (const float*)d_in[8];
    const float* W_hh        = (const float*)d_in[9];
    const float* b_ih        = (const float*)d_in[10];
    const float* b_hh        = (const float*)d_in[11];

    const int n_nodes  = in_sizes[0] / MEMD;
    const int n_events = in_sizes[2];

    float* ACC = (float*)d_ws;
    int*   cnt = (int*)((char*)d_ws + (size_t)n_nodes * ACCD * sizeof(float));
    int*   lu  = cnt + n_nodes;

    const size_t zero_bytes = (size_t)n_nodes * ACCD * sizeof(float) + 2 * (size_t)n_nodes * sizeof(int);
    (void)hipMemsetAsync(d_ws, 0, zero_bytes, stream);

    tgn_scatter<<<dim3((n_events + 1) / 2), dim3(256), 0, stream>>>(
        memory, last_update, src, dst, t, raw_msg, time_w, time_b,
        ACC, cnt, lu, n_events);

    tgn_gru<<<dim3((n_nodes + 63) / 64), dim3(512), 0, stream>>>(
        memory, ACC, cnt, W_ih, W_hh, b_ih, b_hh, (float*)d_out, n_nodes);

    float* out2 = (float*)d_out + (size_t)n_nodes * MEMD;
    tgn_lu_out<<<dim3((n_nodes + 255) / 256), dim3(256), 0, stream>>>(lu, out2, n_nodes);
}

// Round 3
// 871.991 us; speedup vs baseline: 6.1823x; 6.1823x over previous
//
#include <hip/hip_runtime.h>
#include <cstdint>

// TGN memory update: message scatter-mean + GRU cell, MFMA version.
// aggr = [mem_self | ACC/cnt]; gi = (cnt>0 ? X @ W_ih^T : 0) + b_ih,
// gh = mem @ W_hh^T + b_hh; GRU epilogue fused.

#define MEMD 128
#define ACCD 384
#define MSGD 512

typedef __attribute__((ext_vector_type(8))) short bf16x8;
typedef __attribute__((ext_vector_type(4))) float f32x4;

static __device__ __forceinline__ short f2bf(float f) {
    uint32_t u = __builtin_bit_cast(uint32_t, f);
    u = (u + 0x7FFFu + ((u >> 16) & 1u)) >> 16;
    return (short)u;
}

// ---------------- Phase 1: per-event scatter ----------------
__global__ __launch_bounds__(256) void tgn_scatter(
    const float* __restrict__ memory, const int* __restrict__ last_update,
    const int* __restrict__ src, const int* __restrict__ dst, const int* __restrict__ t,
    const float* __restrict__ raw_msg, const float* __restrict__ time_w,
    const float* __restrict__ time_b,
    float* __restrict__ ACC, int* __restrict__ cnt, int* __restrict__ lu_new,
    int n_events)
{
    const int e = blockIdx.x * 2 + (threadIdx.x >> 7);
    if (e >= n_events) return;
    const int j = threadIdx.x & 127;

    const int s = src[e];
    const int d = dst[e];
    const int te = t[e];

    const float tw = time_w[j];
    const float tb = time_b[j];
    const float dts = (float)(te - last_update[s]);
    const float dtd = (float)(te - last_update[d]);
    const float tenc_s = __cosf(fmaf(dts, tw, tb));
    const float tenc_d = __cosf(fmaf(dtd, tw, tb));

    const float ms = memory[(size_t)s * MEMD + j];
    const float md = memory[(size_t)d * MEMD + j];
    const float rw = raw_msg[(size_t)e * MEMD + j];

    float* As = ACC + (size_t)s * ACCD;
    float* Ad = ACC + (size_t)d * ACCD;
    atomicAdd(As + j, md);
    atomicAdd(As + 128 + j, rw);
    atomicAdd(As + 256 + j, tenc_s);
    atomicAdd(Ad + j, ms);
    atomicAdd(Ad + 128 + j, rw);
    atomicAdd(Ad + 256 + j, tenc_d);

    if (j == 0) {
        atomicAdd(cnt + s, 1);
        atomicAdd(cnt + d, 1);
        atomicMax(lu_new + s, te);
        atomicMax(lu_new + d, te);
    }
}

// ---------------- Weight prep: f32 -> bf16 frag-major ----------------
// Wb layout: gi frags [24 ntile][16 kstep][64 lane], then gh frags [24][4][64].
// Frag (n,ks,lane): j = n*16 + (lane&15), k = ks*32 + (lane>>4)*8 .. +7.
#define GI_SLOTS (24 * 16 * 64)
#define GH_SLOTS (24 * 4 * 64)

__global__ __launch_bounds__(256) void tgn_prep_w(
    const float* __restrict__ W_ih, const float* __restrict__ W_hh,
    bf16x8* __restrict__ Wb)
{
    const int s = blockIdx.x * 256 + threadIdx.x;
    if (s >= GI_SLOTS + GH_SLOTS) return;
    const float* src;
    if (s < GI_SLOTS) {
        const int n = s / (16 * 64), rem = s % (16 * 64);
        const int ks = rem / 64, l = rem % 64;
        const int j = n * 16 + (l & 15), k = ks * 32 + (l >> 4) * 8;
        src = W_ih + (size_t)j * MSGD + k;
    } else {
        const int s2 = s - GI_SLOTS;
        const int n = s2 / (4 * 64), rem = s2 % (4 * 64);
        const int ks = rem / 64, l = rem % 64;
        const int j = n * 16 + (l & 15), k = ks * 32 + (l >> 4) * 8;
        src = W_hh + (size_t)j * MEMD + k;
    }
    bf16x8 v;
    #pragma unroll
    for (int e = 0; e < 8; ++e) v[e] = f2bf(src[e]);
    Wb[s] = v;
}

// ---------------- Phase 2: MFMA GEMM + GRU ----------------
// 256 threads (4 waves), 64 nodes/block. X row (512): [mem | ACC/cnt].
// LDS frag-major: Xf[(m*16+ks)*64 + lane] -> linear ds_read_b128, no conflicts.
// Wave w owns N-tiles {w, w+4, ..., w+20}: triples (nl, nl+2, nl+4) give
// (j, j+128, j+256) -> wave-local GRU epilogue.
__global__ __launch_bounds__(256, 2) void tgn_gru_mfma(
    const float* __restrict__ memory, const float* __restrict__ ACC,
    const int* __restrict__ cnt, const bf16x8* __restrict__ Wb,
    const float* __restrict__ b_ih, const float* __restrict__ b_hh,
    float* __restrict__ out, int n_nodes)
{
    __shared__ bf16x8 Xf[4 * 16 * 64]; // 64 KB

    const int tid = threadIdx.x;
    const int lane = tid & 63;
    const int node0 = blockIdx.x * 64;

    // ---- stage X tile as bf16 frags ----
    #pragma unroll
    for (int i = 0; i < 16; ++i) {
        const int slot = i * 256 + tid;
        const int l = slot & 63;
        const int ks = (slot >> 6) & 15;
        const int m = slot >> 10;
        const int node = node0 + m * 16 + (l & 15);
        const int kbase = ks * 32 + (l >> 4) * 8;
        float v0, v1, v2, v3, v4, v5, v6, v7;
        if (kbase < 128) {
            const float4 pa = *reinterpret_cast<const float4*>(memory + (size_t)node * MEMD + kbase);
            const float4 pb = *reinterpret_cast<const float4*>(memory + (size_t)node * MEMD + kbase + 4);
            v0 = pa.x; v1 = pa.y; v2 = pa.z; v3 = pa.w;
            v4 = pb.x; v5 = pb.y; v6 = pb.z; v7 = pb.w;
        } else {
            const int c = cnt[node];
            const float inv = (c > 0) ? 1.0f / (float)c : 0.0f;
            const float4 pa = *reinterpret_cast<const float4*>(ACC + (size_t)node * ACCD + (kbase - 128));
            const float4 pb = *reinterpret_cast<const float4*>(ACC + (size_t)node * ACCD + (kbase - 128) + 4);
            v0 = pa.x * inv; v1 = pa.y * inv; v2 = pa.z * inv; v3 = pa.w * inv;
            v4 = pb.x * inv; v5 = pb.y * inv; v6 = pb.z * inv; v7 = pb.w * inv;
        }
        bf16x8 xv;
        xv[0] = f2bf(v0); xv[1] = f2bf(v1); xv[2] = f2bf(v2); xv[3] = f2bf(v3);
        xv[4] = f2bf(v4); xv[5] = f2bf(v5); xv[6] = f2bf(v6); xv[7] = f2bf(v7);
        Xf[slot] = xv;
    }
    __syncthreads();

    const int wv = __builtin_amdgcn_readfirstlane(tid >> 6); // 0..3
    const int col = lane & 15;
    const int rgrp = lane >> 4;

    f32x4 acc_i[6][4];
    #pragma unroll
    for (int nl = 0; nl < 6; ++nl)
        #pragma unroll
        for (int m = 0; m < 4; ++m) acc_i[nl][m] = (f32x4){0.f, 0.f, 0.f, 0.f};

    // gi: K = 512 (16 k-steps)
    for (int ks = 0; ks < 16; ++ks) {
        bf16x8 a[4];
        #pragma unroll
        for (int m = 0; m < 4; ++m) a[m] = Xf[(m * 16 + ks) * 64 + lane];
        #pragma unroll
        for (int nl = 0; nl < 6; ++nl) {
            const bf16x8 b = Wb[((wv + nl * 4) * 16 + ks) * 64 + lane];
            #pragma unroll
            for (int m = 0; m < 4; ++m)
                acc_i[nl][m] = __builtin_amdgcn_mfma_f32_16x16x32_bf16(a[m], b, acc_i[nl][m], 0, 0, 0);
        }
    }

    f32x4 acc_h[6][4];
    #pragma unroll
    for (int nl = 0; nl < 6; ++nl)
        #pragma unroll
        for (int m = 0; m < 4; ++m) acc_h[nl][m] = (f32x4){0.f, 0.f, 0.f, 0.f};

    // gh: K = 128 (k-steps 0..3 of the same staged X)
    const bf16x8* __restrict__ Wh = Wb + GI_SLOTS;
    for (int ks = 0; ks < 4; ++ks) {
        bf16x8 a[4];
        #pragma unroll
        for (int m = 0; m < 4; ++m) a[m] = Xf[(m * 16 + ks) * 64 + lane];
        #pragma unroll
        for (int nl = 0; nl < 6; ++nl) {
            const bf16x8 b = Wh[((wv + nl * 4) * 4 + ks) * 64 + lane];
            #pragma unroll
            for (int m = 0; m < 4; ++m)
                acc_h[nl][m] = __builtin_amdgcn_mfma_f32_16x16x32_bf16(a[m], b, acc_h[nl][m], 0, 0, 0);
        }
    }

    // ---- GRU epilogue (wave-local) ----
    bool has[4][4];
    #pragma unroll
    for (int m = 0; m < 4; ++m)
        #pragma unroll
        for (int r = 0; r < 4; ++r)
            has[m][r] = cnt[node0 + m * 16 + rgrp * 4 + r] > 0;

    #pragma unroll
    for (int tpl = 0; tpl < 2; ++tpl) {
        const int jr = (wv + 4 * tpl) * 16 + col; // 0..127
        const float bir = b_ih[jr], biz = b_ih[jr + 128], bin = b_ih[jr + 256];
        const float bhr = b_hh[jr], bhz = b_hh[jr + 128], bhn = b_hh[jr + 256];
        #pragma unroll
        for (int m = 0; m < 4; ++m) {
            #pragma unroll
            for (int r = 0; r < 4; ++r) {
                const int node = node0 + m * 16 + rgrp * 4 + r;
                const float gir = (has[m][r] ? acc_i[tpl][m][r] : 0.f) + bir;
                const float giz = (has[m][r] ? acc_i[tpl + 2][m][r] : 0.f) + biz;
                const float gin = (has[m][r] ? acc_i[tpl + 4][m][r] : 0.f) + bin;
                const float ghr = acc_h[tpl][m][r] + bhr;
                const float ghz = acc_h[tpl + 2][m][r] + bhz;
                const float ghn = acc_h[tpl + 4][m][r] + bhn;
                const float rr = 1.0f / (1.0f + __expf(-(gir + ghr)));
                const float zz = 1.0f / (1.0f + __expf(-(giz + ghz)));
                const float nn = tanhf(fmaf(rr, ghn, gin));
                const float mv = memory[(size_t)node * MEMD + jr];
                out[(size_t)node * MEMD + jr] = (1.0f - zz) * nn + zz * mv;
            }
        }
    }
}

// ---------------- Phase 3: last_update -> float out ----------------
__global__ void tgn_lu_out(const int* __restrict__ lu, float* __restrict__ out2, int n_nodes)
{
    const int i = blockIdx.x * blockDim.x + threadIdx.x;
    if (i < n_nodes) out2[i] = (float)lu[i];
}

extern "C" void kernel_launch(void* const* d_in, const int* in_sizes, int n_in,
                              void* d_out, int out_size, void* d_ws, size_t ws_size,
                              hipStream_t stream)
{
    const float* memory      = (const float*)d_in[0];
    const int*   last_update = (const int*)d_in[1];
    const int*   src         = (const int*)d_in[2];
    const int*   dst         = (const int*)d_in[3];
    const int*   t           = (const int*)d_in[4];
    const float* raw_msg     = (const float*)d_in[5];
    const float* time_w      = (const float*)d_in[6];
    const float* time_b      = (const float*)d_in[7];
    const float* W_ih        = (const float*)d_in[8];
    const float* W_hh        = (const float*)d_in[9];
    const float* b_ih        = (const float*)d_in[10];
    const float* b_hh        = (const float*)d_in[11];

    const int n_nodes  = in_sizes[0] / MEMD;
    const int n_events = in_sizes[2];

    float* ACC = (float*)d_ws;
    int*   cnt = (int*)((char*)d_ws + (size_t)n_nodes * ACCD * sizeof(float));
    int*   lu  = cnt + n_nodes;
    bf16x8* Wb = (bf16x8*)(lu + n_nodes);

    const size_t zero_bytes = (size_t)n_nodes * ACCD * sizeof(float) + 2 * (size_t)n_nodes * sizeof(int);
    (void)hipMemsetAsync(d_ws, 0, zero_bytes, stream);

    tgn_prep_w<<<dim3((GI_SLOTS + GH_SLOTS + 255) / 256), dim3(256), 0, stream>>>(W_ih, W_hh, Wb);

    tgn_scatter<<<dim3((n_events + 1) / 2), dim3(256), 0, stream>>>(
        memory, last_update, src, dst, t, raw_msg, time_w, time_b,
        ACC, cnt, lu, n_events);

    tgn_gru_mfma<<<dim3(n_nodes / 64), dim3(256), 0, stream>>>(
        memory, ACC, cnt, Wb, b_ih, b_hh, (float*)d_out, n_nodes);

    float* out2 = (float*)d_out + (size_t)n_nodes * MEMD;
    tgn_lu_out<<<dim3((n_nodes + 255) / 256), dim3(256), 0, stream>>>(lu, out2, n_nodes);
}

// Round 4
// 701.949 us; speedup vs baseline: 7.6800x; 1.2422x over previous
//
#include <hip/hip_runtime.h>
#include <cstdint>

// TGN memory update: message scatter-mean (bf16 packed atomics) + MFMA GRU.
// aggr = [mem_self | ACC/cnt]; gi = (cnt>0 ? X @ W_ih^T : 0) + b_ih,
// gh = mem @ W_hh^T + b_hh; GRU epilogue fused.

#define MEMD 128
#define ACCD 384
#define MSGD 512

typedef __attribute__((ext_vector_type(8))) short bf16x8;
typedef __attribute__((ext_vector_type(2))) short bf16x2;
typedef __attribute__((ext_vector_type(4))) float f32x4;

static __device__ __forceinline__ short f2bf(float f) {
    uint32_t u = __builtin_bit_cast(uint32_t, f);
    u = (u + 0x7FFFu + ((u >> 16) & 1u)) >> 16;
    return (short)u;
}
static __device__ __forceinline__ float bf2f(short s) {
    return __builtin_bit_cast(float, ((uint32_t)(uint16_t)s) << 16);
}
static __device__ __forceinline__ void atomic_pk_add_bf16(short* p, bf16x2 v) {
    const uint64_t addr = (uint64_t)p;
    asm volatile("global_atomic_pk_add_bf16 %0, %1, off" :: "v"(addr), "v"(v) : "memory");
}

// ---------------- Prep A: memory f32 -> bf16 ----------------
__global__ __launch_bounds__(256) void tgn_prep_mem(
    const float* __restrict__ mem, short* __restrict__ memB, int n8)
{
    const int i = blockIdx.x * 256 + threadIdx.x;
    if (i >= n8) return;
    const float4 a = *reinterpret_cast<const float4*>(mem + (size_t)i * 8);
    const float4 b = *reinterpret_cast<const float4*>(mem + (size_t)i * 8 + 4);
    bf16x8 v;
    v[0] = f2bf(a.x); v[1] = f2bf(a.y); v[2] = f2bf(a.z); v[3] = f2bf(a.w);
    v[4] = f2bf(b.x); v[5] = f2bf(b.y); v[6] = f2bf(b.z); v[7] = f2bf(b.w);
    *reinterpret_cast<bf16x8*>(memB + (size_t)i * 8) = v;
}

// ---------------- Prep B: weights f32 -> bf16 frag-major ----------------
// Wb: gi frags [24 ntile][16 kstep][64 lane], then gh frags [24][4][64].
// Frag (n,ks,lane): j = n*16 + (lane&15), k = ks*32 + (lane>>4)*8 .. +7.
#define GI_SLOTS (24 * 16 * 64)
#define GH_SLOTS (24 * 4 * 64)

__global__ __launch_bounds__(256) void tgn_prep_w(
    const float* __restrict__ W_ih, const float* __restrict__ W_hh,
    bf16x8* __restrict__ Wb)
{
    const int s = blockIdx.x * 256 + threadIdx.x;
    if (s >= GI_SLOTS + GH_SLOTS) return;
    const float* src;
    if (s < GI_SLOTS) {
        const int n = s / (16 * 64), rem = s % (16 * 64);
        const int ks = rem / 64, l = rem % 64;
        const int j = n * 16 + (l & 15), k = ks * 32 + (l >> 4) * 8;
        src = W_ih + (size_t)j * MSGD + k;
    } else {
        const int s2 = s - GI_SLOTS;
        const int n = s2 / (4 * 64), rem = s2 % (4 * 64);
        const int ks = rem / 64, l = rem % 64;
        const int j = n * 16 + (l & 15), k = ks * 32 + (l >> 4) * 8;
        src = W_hh + (size_t)j * MEMD + k;
    }
    bf16x8 v;
    #pragma unroll
    for (int e = 0; e < 8; ++e) v[e] = f2bf(src[e]);
    Wb[s] = v;
}

// ---------------- Phase 1: per-event scatter (packed bf16 atomics) --------
// 64 lanes per event, 2 feature dims per lane; 4 events per 256-block.
__global__ __launch_bounds__(256) void tgn_scatter(
    const short* __restrict__ memB, const int* __restrict__ last_update,
    const int* __restrict__ src, const int* __restrict__ dst, const int* __restrict__ t,
    const float* __restrict__ raw_msg, const float* __restrict__ time_w,
    const float* __restrict__ time_b,
    short* __restrict__ ACC, int* __restrict__ cnt, int* __restrict__ lu_new,
    int n_events)
{
    const int e = blockIdx.x * 4 + (threadIdx.x >> 6);
    if (e >= n_events) return;
    const int l = threadIdx.x & 63;
    const int j0 = l * 2;

    const int s = src[e];
    const int d = dst[e];
    const int te = t[e];

    const float2 tw = *reinterpret_cast<const float2*>(time_w + j0);
    const float2 tb = *reinterpret_cast<const float2*>(time_b + j0);
    const float dts = (float)(te - last_update[s]);
    const float dtd = (float)(te - last_update[d]);
    bf16x2 tenc_s, tenc_d, rb;
    tenc_s[0] = f2bf(__cosf(fmaf(dts, tw.x, tb.x)));
    tenc_s[1] = f2bf(__cosf(fmaf(dts, tw.y, tb.y)));
    tenc_d[0] = f2bf(__cosf(fmaf(dtd, tw.x, tb.x)));
    tenc_d[1] = f2bf(__cosf(fmaf(dtd, tw.y, tb.y)));

    const bf16x2 ms2 = *reinterpret_cast<const bf16x2*>(memB + (size_t)s * MEMD + j0);
    const bf16x2 md2 = *reinterpret_cast<const bf16x2*>(memB + (size_t)d * MEMD + j0);
    const float2 rw = *reinterpret_cast<const float2*>(raw_msg + (size_t)e * MEMD + j0);
    rb[0] = f2bf(rw.x); rb[1] = f2bf(rw.y);

    short* As = ACC + (size_t)s * ACCD;
    short* Ad = ACC + (size_t)d * ACCD;
    atomic_pk_add_bf16(As + j0, md2);
    atomic_pk_add_bf16(As + 128 + j0, rb);
    atomic_pk_add_bf16(As + 256 + j0, tenc_s);
    atomic_pk_add_bf16(Ad + j0, ms2);
    atomic_pk_add_bf16(Ad + 128 + j0, rb);
    atomic_pk_add_bf16(Ad + 256 + j0, tenc_d);

    if (l == 0) {
        atomicAdd(cnt + s, 1);
        atomicAdd(cnt + d, 1);
        atomicMax(lu_new + s, te);
        atomicMax(lu_new + d, te);
    }
}

// ---------------- Phase 2: MFMA GEMM + GRU ----------------
// 256 threads (4 waves), 32 nodes/block, 32 KB LDS -> 4 blocks/CU.
// Xf frag-major: [(m*16+ks)*64 + lane] -> linear, conflict-free b128.
// Wave w owns N-tiles {w, w+4, ..., w+20}; triples (tpl, tpl+2, tpl+4) give
// (j, j+128, j+256) -> wave-local GRU epilogue.
__global__ __launch_bounds__(256, 4) void tgn_gru_mfma(
    const short* __restrict__ memB, const short* __restrict__ ACC,
    const int* __restrict__ cnt, const bf16x8* __restrict__ Wb,
    const float* __restrict__ b_ih, const float* __restrict__ b_hh,
    float* __restrict__ out, int n_nodes)
{
    __shared__ bf16x8 Xf[2 * 16 * 64]; // 32 KB

    const int tid = threadIdx.x;
    const int lane = tid & 63;
    const int node0 = blockIdx.x * 32;

    // ---- stage X tile (already bf16; scale ACC part by 1/cnt) ----
    #pragma unroll
    for (int i = 0; i < 8; ++i) {
        const int slot = i * 256 + tid;      // 0..2047
        const int l = slot & 63;
        const int ks = (slot >> 6) & 15;
        const int m = slot >> 10;            // 0..1
        int node = node0 + m * 16 + (l & 15);
        if (node >= n_nodes) node = n_nodes - 1;
        const int kbase = ks * 32 + (l >> 4) * 8;
        bf16x8 xv;
        if (kbase < 128) {
            xv = *reinterpret_cast<const bf16x8*>(memB + (size_t)node * MEMD + kbase);
        } else {
            const int c = cnt[node];
            const float inv = (c > 0) ? 1.0f / (float)c : 0.0f;
            const bf16x8 av = *reinterpret_cast<const bf16x8*>(ACC + (size_t)node * ACCD + (kbase - 128));
            #pragma unroll
            for (int e2 = 0; e2 < 8; ++e2) xv[e2] = f2bf(bf2f(av[e2]) * inv);
        }
        Xf[slot] = xv;
    }
    __syncthreads();

    const int wv = __builtin_amdgcn_readfirstlane(tid >> 6); // 0..3
    const int col = lane & 15;
    const int rgrp = lane >> 4;

    f32x4 acc_i[6][2], acc_h[6][2];
    #pragma unroll
    for (int nl = 0; nl < 6; ++nl)
        #pragma unroll
        for (int m = 0; m < 2; ++m) {
            acc_i[nl][m] = (f32x4){0.f, 0.f, 0.f, 0.f};
            acc_h[nl][m] = (f32x4){0.f, 0.f, 0.f, 0.f};
        }

    const bf16x8* __restrict__ Wh = Wb + GI_SLOTS;

    // K-steps 0..3: both gi (K=512) and gh (K=128) share A-frags
    for (int ks = 0; ks < 4; ++ks) {
        bf16x8 a[2];
        #pragma unroll
        for (int m = 0; m < 2; ++m) a[m] = Xf[(m * 16 + ks) * 64 + lane];
        #pragma unroll
        for (int nl = 0; nl < 6; ++nl) {
            const bf16x8 bi = Wb[((wv + nl * 4) * 16 + ks) * 64 + lane];
            const bf16x8 bh = Wh[((wv + nl * 4) * 4 + ks) * 64 + lane];
            #pragma unroll
            for (int m = 0; m < 2; ++m) {
                acc_i[nl][m] = __builtin_amdgcn_mfma_f32_16x16x32_bf16(a[m], bi, acc_i[nl][m], 0, 0, 0);
                acc_h[nl][m] = __builtin_amdgcn_mfma_f32_16x16x32_bf16(a[m], bh, acc_h[nl][m], 0, 0, 0);
            }
        }
    }
    // K-steps 4..15: gi only
    for (int ks = 4; ks < 16; ++ks) {
        bf16x8 a[2];
        #pragma unroll
        for (int m = 0; m < 2; ++m) a[m] = Xf[(m * 16 + ks) * 64 + lane];
        #pragma unroll
        for (int nl = 0; nl < 6; ++nl) {
            const bf16x8 bi = Wb[((wv + nl * 4) * 16 + ks) * 64 + lane];
            #pragma unroll
            for (int m = 0; m < 2; ++m)
                acc_i[nl][m] = __builtin_amdgcn_mfma_f32_16x16x32_bf16(a[m], bi, acc_i[nl][m], 0, 0, 0);
        }
    }

    // ---- GRU epilogue (wave-local) ----
    bool has[2][4];
    #pragma unroll
    for (int m = 0; m < 2; ++m)
        #pragma unroll
        for (int r = 0; r < 4; ++r) {
            int node = node0 + m * 16 + rgrp * 4 + r;
            has[m][r] = (node < n_nodes) && (cnt[node] > 0);
        }

    #pragma unroll
    for (int tpl = 0; tpl < 2; ++tpl) {
        const int jr = (wv + 4 * tpl) * 16 + col; // 0..127
        const float bir = b_ih[jr], biz = b_ih[jr + 128], bin = b_ih[jr + 256];
        const float bhr = b_hh[jr], bhz = b_hh[jr + 128], bhn = b_hh[jr + 256];
        #pragma unroll
        for (int m = 0; m < 2; ++m) {
            #pragma unroll
            for (int r = 0; r < 4; ++r) {
                const int node = node0 + m * 16 + rgrp * 4 + r;
                if (node >= n_nodes) continue;
                const float gir = (has[m][r] ? acc_i[tpl][m][r] : 0.f) + bir;
                const float giz = (has[m][r] ? acc_i[tpl + 2][m][r] : 0.f) + biz;
                const float gin = (has[m][r] ? acc_i[tpl + 4][m][r] : 0.f) + bin;
                const float ghr = acc_h[tpl][m][r] + bhr;
                const float ghz = acc_h[tpl + 2][m][r] + bhz;
                const float ghn = acc_h[tpl + 4][m][r] + bhn;
                const float rr = 1.0f / (1.0f + __expf(-(gir + ghr)));
                const float zz = 1.0f / (1.0f + __expf(-(giz + ghz)));
                const float nn = tanhf(fmaf(rr, ghn, gin));
                const float mv = bf2f(memB[(size_t)node * MEMD + jr]);
                out[(size_t)node * MEMD + jr] = (1.0f - zz) * nn + zz * mv;
            }
        }
    }
}

// ---------------- Phase 3: last_update -> float out ----------------
__global__ void tgn_lu_out(const int* __restrict__ lu, float* __restrict__ out2, int n_nodes)
{
    const int i = blockIdx.x * blockDim.x + threadIdx.x;
    if (i < n_nodes) out2[i] = (float)lu[i];
}

extern "C" void kernel_launch(void* const* d_in, const int* in_sizes, int n_in,
                              void* d_out, int out_size, void* d_ws, size_t ws_size,
                              hipStream_t stream)
{
    const float* memory      = (const float*)d_in[0];
    const int*   last_update = (const int*)d_in[1];
    const int*   src         = (const int*)d_in[2];
    const int*   dst         = (const int*)d_in[3];
    const int*   t           = (const int*)d_in[4];
    const float* raw_msg     = (const float*)d_in[5];
    const float* time_w      = (const float*)d_in[6];
    const float* time_b      = (const float*)d_in[7];
    const float* W_ih        = (const float*)d_in[8];
    const float* W_hh        = (const float*)d_in[9];
    const float* b_ih        = (const float*)d_in[10];
    const float* b_hh        = (const float*)d_in[11];

    const int n_nodes  = in_sizes[0] / MEMD;
    const int n_events = in_sizes[2];

    // Workspace layout: ACC(bf16) | cnt | lu | Wb | memB
    short* ACC = (short*)d_ws;
    int*   cnt = (int*)((char*)d_ws + (size_t)n_nodes * ACCD * sizeof(short));
    int*   lu  = cnt + n_nodes;
    bf16x8* Wb = (bf16x8*)(lu + n_nodes);
    short* memB = (short*)(Wb + GI_SLOTS + GH_SLOTS);

    const size_t zero_bytes = (size_t)n_nodes * ACCD * sizeof(short) + 2 * (size_t)n_nodes * sizeof(int);
    (void)hipMemsetAsync(d_ws, 0, zero_bytes, stream);

    tgn_prep_w<<<dim3((GI_SLOTS + GH_SLOTS + 255) / 256), dim3(256), 0, stream>>>(W_ih, W_hh, Wb);

    const int n8 = n_nodes * MEMD / 8;
    tgn_prep_mem<<<dim3((n8 + 255) / 256), dim3(256), 0, stream>>>(memory, memB, n8);

    tgn_scatter<<<dim3((n_events + 3) / 4), dim3(256), 0, stream>>>(
        memB, last_update, src, dst, t, raw_msg, time_w, time_b,
        ACC, cnt, lu, n_events);

    tgn_gru_mfma<<<dim3((n_nodes + 31) / 32), dim3(256), 0, stream>>>(
        memB, ACC, cnt, Wb, b_ih, b_hh, (float*)d_out, n_nodes);

    float* out2 = (float*)d_out + (size_t)n_nodes * MEMD;
    tgn_lu_out<<<dim3((n_nodes + 255) / 256), dim3(256), 0, stream>>>(lu, out2, n_nodes);
}

// Round 5
// 697.964 us; speedup vs baseline: 7.7238x; 1.0057x over previous
//
#include <hip/hip_runtime.h>
#include <cstdint>

// TGN memory update: message scatter-mean (bf16 packed atomics) + MFMA GRU.
// aggr = [mem_self | ACC/cnt]; gi = (cnt>0 ? X @ W_ih^T : 0) + b_ih,
// gh = mem @ W_hh^T + b_hh; GRU epilogue fused, output via LDS-coalesced store.

#define MEMD 128
#define ACCD 384
#define MSGD 512

typedef __attribute__((ext_vector_type(8))) short bf16x8;
typedef __attribute__((ext_vector_type(2))) short bf16x2;
typedef __attribute__((ext_vector_type(4))) float f32x4;

static __device__ __forceinline__ short f2bf(float f) {
    uint32_t u = __builtin_bit_cast(uint32_t, f);
    u = (u + 0x7FFFu + ((u >> 16) & 1u)) >> 16;
    return (short)u;
}
static __device__ __forceinline__ float bf2f(short s) {
    return __builtin_bit_cast(float, ((uint32_t)(uint16_t)s) << 16);
}
static __device__ __forceinline__ void atomic_pk_add_bf16(short* p, bf16x2 v) {
    const uint64_t addr = (uint64_t)p;
    asm volatile("global_atomic_pk_add_bf16 %0, %1, off" :: "v"(addr), "v"(v) : "memory");
}

// ---------------- Prep A: memory f32 -> bf16 ----------------
__global__ __launch_bounds__(256) void tgn_prep_mem(
    const float* __restrict__ mem, short* __restrict__ memB, int n8)
{
    const int i = blockIdx.x * 256 + threadIdx.x;
    if (i >= n8) return;
    const float4 a = *reinterpret_cast<const float4*>(mem + (size_t)i * 8);
    const float4 b = *reinterpret_cast<const float4*>(mem + (size_t)i * 8 + 4);
    bf16x8 v;
    v[0] = f2bf(a.x); v[1] = f2bf(a.y); v[2] = f2bf(a.z); v[3] = f2bf(a.w);
    v[4] = f2bf(b.x); v[5] = f2bf(b.y); v[6] = f2bf(b.z); v[7] = f2bf(b.w);
    *reinterpret_cast<bf16x8*>(memB + (size_t)i * 8) = v;
}

// ---------------- Prep B: weights f32 -> bf16 frag-major ----------------
// Wb: gi frags [24 ntile][16 kstep][64 lane], then gh frags [24][4][64].
// Frag (n,ks,lane): j = n*16 + (lane&15), k = ks*32 + (lane>>4)*8 .. +7.
#define GI_SLOTS (24 * 16 * 64)
#define GH_SLOTS (24 * 4 * 64)

__global__ __launch_bounds__(256) void tgn_prep_w(
    const float* __restrict__ W_ih, const float* __restrict__ W_hh,
    bf16x8* __restrict__ Wb)
{
    const int s = blockIdx.x * 256 + threadIdx.x;
    if (s >= GI_SLOTS + GH_SLOTS) return;
    const float* src;
    if (s < GI_SLOTS) {
        const int n = s / (16 * 64), rem = s % (16 * 64);
        const int ks = rem / 64, l = rem % 64;
        const int j = n * 16 + (l & 15), k = ks * 32 + (l >> 4) * 8;
        src = W_ih + (size_t)j * MSGD + k;
    } else {
        const int s2 = s - GI_SLOTS;
        const int n = s2 / (4 * 64), rem = s2 % (4 * 64);
        const int ks = rem / 64, l = rem % 64;
        const int j = n * 16 + (l & 15), k = ks * 32 + (l >> 4) * 8;
        src = W_hh + (size_t)j * MEMD + k;
    }
    bf16x8 v;
    #pragma unroll
    for (int e = 0; e < 8; ++e) v[e] = f2bf(src[e]);
    Wb[s] = v;
}

// ---------------- Phase 1: per-event scatter (packed bf16 atomics) --------
__global__ __launch_bounds__(256) void tgn_scatter(
    const short* __restrict__ memB, const int* __restrict__ last_update,
    const int* __restrict__ src, const int* __restrict__ dst, const int* __restrict__ t,
    const float* __restrict__ raw_msg, const float* __restrict__ time_w,
    const float* __restrict__ time_b,
    short* __restrict__ ACC, int* __restrict__ cnt, int* __restrict__ lu_new,
    int n_events)
{
    const int e = blockIdx.x * 4 + (threadIdx.x >> 6);
    if (e >= n_events) return;
    const int l = threadIdx.x & 63;
    const int j0 = l * 2;

    const int s = src[e];
    const int d = dst[e];
    const int te = t[e];

    const float2 tw = *reinterpret_cast<const float2*>(time_w + j0);
    const float2 tb = *reinterpret_cast<const float2*>(time_b + j0);
    const float dts = (float)(te - last_update[s]);
    const float dtd = (float)(te - last_update[d]);
    bf16x2 tenc_s, tenc_d, rb;
    tenc_s[0] = f2bf(__cosf(fmaf(dts, tw.x, tb.x)));
    tenc_s[1] = f2bf(__cosf(fmaf(dts, tw.y, tb.y)));
    tenc_d[0] = f2bf(__cosf(fmaf(dtd, tw.x, tb.x)));
    tenc_d[1] = f2bf(__cosf(fmaf(dtd, tw.y, tb.y)));

    const bf16x2 ms2 = *reinterpret_cast<const bf16x2*>(memB + (size_t)s * MEMD + j0);
    const bf16x2 md2 = *reinterpret_cast<const bf16x2*>(memB + (size_t)d * MEMD + j0);
    const float2 rw = *reinterpret_cast<const float2*>(raw_msg + (size_t)e * MEMD + j0);
    rb[0] = f2bf(rw.x); rb[1] = f2bf(rw.y);

    short* As = ACC + (size_t)s * ACCD;
    short* Ad = ACC + (size_t)d * ACCD;
    atomic_pk_add_bf16(As + j0, md2);
    atomic_pk_add_bf16(As + 128 + j0, rb);
    atomic_pk_add_bf16(As + 256 + j0, tenc_s);
    atomic_pk_add_bf16(Ad + j0, ms2);
    atomic_pk_add_bf16(Ad + 128 + j0, rb);
    atomic_pk_add_bf16(Ad + 256 + j0, tenc_d);

    if (l == 0) {
        atomicAdd(cnt + s, 1);
        atomicAdd(cnt + d, 1);
        atomicMax(lu_new + s, te);
        atomicMax(lu_new + d, te);
    }
}

// ---------------- Phase 2: MFMA GEMM + GRU ----------------
// 256 threads (4 waves), 32 nodes/block, 32 KB LDS (Xf, reused as Sout).
// Wave w owns N-tiles {w, w+4, ..., w+20}; triples (tpl, tpl+2, tpl+4) give
// (j, j+128, j+256) -> wave-local GRU epilogue.
__global__ __launch_bounds__(256, 4) void tgn_gru_mfma(
    const short* __restrict__ memB, const short* __restrict__ ACC,
    const int* __restrict__ cnt, const bf16x8* __restrict__ Wb,
    const float* __restrict__ b_ih, const float* __restrict__ b_hh,
    float* __restrict__ out, int n_nodes)
{
    __shared__ __align__(16) char smem_raw[32768];
    bf16x8* Xf   = reinterpret_cast<bf16x8*>(smem_raw);   // [2*16*64] frags
    ushort* Xh   = reinterpret_cast<ushort*>(smem_raw);   // u16 view for mv
    float*  Sout = reinterpret_cast<float*>(smem_raw);    // 32x128 f32 after reuse

    const int tid = threadIdx.x;
    const int lane = tid & 63;
    const int node0 = blockIdx.x * 32;

    // ---- stage X tile (bf16; scale ACC part by 1/cnt) ----
    #pragma unroll
    for (int i = 0; i < 8; ++i) {
        const int slot = i * 256 + tid;      // 0..2047
        const int l = slot & 63;
        const int ks = (slot >> 6) & 15;
        const int m = slot >> 10;            // 0..1
        int node = node0 + m * 16 + (l & 15);
        if (node >= n_nodes) node = n_nodes - 1;
        const int kbase = ks * 32 + (l >> 4) * 8;
        bf16x8 xv;
        if (kbase < 128) {
            xv = *reinterpret_cast<const bf16x8*>(memB + (size_t)node * MEMD + kbase);
        } else {
            const int c = cnt[node];
            const float inv = (c > 0) ? 1.0f / (float)c : 0.0f;
            const bf16x8 av = *reinterpret_cast<const bf16x8*>(ACC + (size_t)node * ACCD + (kbase - 128));
            #pragma unroll
            for (int e2 = 0; e2 < 8; ++e2) xv[e2] = f2bf(bf2f(av[e2]) * inv);
        }
        Xf[slot] = xv;
    }
    __syncthreads();

    const int wv = __builtin_amdgcn_readfirstlane(tid >> 6); // 0..3
    const int col = lane & 15;
    const int rgrp = lane >> 4;

    f32x4 acc_i[6][2], acc_h[6][2];
    #pragma unroll
    for (int nl = 0; nl < 6; ++nl)
        #pragma unroll
        for (int m = 0; m < 2; ++m) {
            acc_i[nl][m] = (f32x4){0.f, 0.f, 0.f, 0.f};
            acc_h[nl][m] = (f32x4){0.f, 0.f, 0.f, 0.f};
        }

    const bf16x8* __restrict__ Wh = Wb + GI_SLOTS;

    // K-steps 0..3: both gi (K=512) and gh (K=128) share A-frags
    for (int ks = 0; ks < 4; ++ks) {
        bf16x8 a[2];
        #pragma unroll
        for (int m = 0; m < 2; ++m) a[m] = Xf[(m * 16 + ks) * 64 + lane];
        #pragma unroll
        for (int nl = 0; nl < 6; ++nl) {
            const bf16x8 bi = Wb[((wv + nl * 4) * 16 + ks) * 64 + lane];
            const bf16x8 bh = Wh[((wv + nl * 4) * 4 + ks) * 64 + lane];
            #pragma unroll
            for (int m = 0; m < 2; ++m) {
                acc_i[nl][m] = __builtin_amdgcn_mfma_f32_16x16x32_bf16(a[m], bi, acc_i[nl][m], 0, 0, 0);
                acc_h[nl][m] = __builtin_amdgcn_mfma_f32_16x16x32_bf16(a[m], bh, acc_h[nl][m], 0, 0, 0);
            }
        }
    }
    // K-steps 4..15: gi only
    for (int ks = 4; ks < 16; ++ks) {
        bf16x8 a[2];
        #pragma unroll
        for (int m = 0; m < 2; ++m) a[m] = Xf[(m * 16 + ks) * 64 + lane];
        #pragma unroll
        for (int nl = 0; nl < 6; ++nl) {
            const bf16x8 bi = Wb[((wv + nl * 4) * 16 + ks) * 64 + lane];
            #pragma unroll
            for (int m = 0; m < 2; ++m)
                acc_i[nl][m] = __builtin_amdgcn_mfma_f32_16x16x32_bf16(a[m], bi, acc_i[nl][m], 0, 0, 0);
        }
    }

    // ---- GRU epilogue (wave-local, results to registers) ----
    bool has[2][4];
    #pragma unroll
    for (int m = 0; m < 2; ++m)
        #pragma unroll
        for (int r = 0; r < 4; ++r) {
            int node = node0 + m * 16 + rgrp * 4 + r;
            has[m][r] = (node < n_nodes) && (cnt[node] > 0);
        }

    float rout[2][2][4];
    #pragma unroll
    for (int tpl = 0; tpl < 2; ++tpl) {
        const int jr = (wv + 4 * tpl) * 16 + col; // 0..127
        const float bir = b_ih[jr], biz = b_ih[jr + 128], bin = b_ih[jr + 256];
        const float bhr = b_hh[jr], bhz = b_hh[jr + 128], bhn = b_hh[jr + 256];
        const int ksj = jr >> 5;            // mem part k-step (0..3)
        const int sub = ((jr >> 3) & 3) * 16;
        const int elem = jr & 7;
        #pragma unroll
        for (int m = 0; m < 2; ++m) {
            #pragma unroll
            for (int r = 0; r < 4; ++r) {
                const float gir = (has[m][r] ? acc_i[tpl][m][r] : 0.f) + bir;
                const float giz = (has[m][r] ? acc_i[tpl + 2][m][r] : 0.f) + biz;
                const float gin = (has[m][r] ? acc_i[tpl + 4][m][r] : 0.f) + bin;
                const float ghr = acc_h[tpl][m][r] + bhr;
                const float ghz = acc_h[tpl + 2][m][r] + bhz;
                const float ghn = acc_h[tpl + 4][m][r] + bhn;
                const float rr = 1.0f / (1.0f + __expf(-(gir + ghr)));
                const float zz = 1.0f / (1.0f + __expf(-(giz + ghz)));
                const float nn = tanhf(fmaf(rr, ghn, gin));
                // mem value from the staged LDS tile (k-steps 0..3 hold mem row)
                const int slot = (m * 16 + ksj) * 64 + sub + (rgrp * 4 + r);
                const float mv = bf2f((short)Xh[slot * 8 + elem]);
                rout[tpl][m][r] = (1.0f - zz) * nn + zz * mv;
            }
        }
    }
    __syncthreads();

    // ---- scatter results to LDS f32 tile [32 nodes][128 cols] ----
    #pragma unroll
    for (int tpl = 0; tpl < 2; ++tpl) {
        const int jr = (wv + 4 * tpl) * 16 + col;
        #pragma unroll
        for (int m = 0; m < 2; ++m)
            #pragma unroll
            for (int r = 0; r < 4; ++r)
                Sout[(m * 16 + rgrp * 4 + r) * MEMD + jr] = rout[tpl][m][r];
    }
    __syncthreads();

    // ---- fully-coalesced float4 write-out ----
    float4* out4 = reinterpret_cast<float4*>(out + (size_t)node0 * MEMD);
    const float4* S4 = reinterpret_cast<const float4*>(Sout);
    if (node0 + 32 <= n_nodes) {
        #pragma unroll
        for (int it = 0; it < 4; ++it)
            out4[it * 256 + tid] = S4[it * 256 + tid];
    } else {
        #pragma unroll
        for (int it = 0; it < 4; ++it) {
            const int idx = it * 256 + tid;             // float4 index in tile
            if (node0 + (idx >> 5) < n_nodes) out4[idx] = S4[idx];
        }
    }
}

// ---------------- Phase 3: last_update -> float out ----------------
__global__ void tgn_lu_out(const int* __restrict__ lu, float* __restrict__ out2, int n_nodes)
{
    const int i = blockIdx.x * blockDim.x + threadIdx.x;
    if (i < n_nodes) out2[i] = (float)lu[i];
}

extern "C" void kernel_launch(void* const* d_in, const int* in_sizes, int n_in,
                              void* d_out, int out_size, void* d_ws, size_t ws_size,
                              hipStream_t stream)
{
    const float* memory      = (const float*)d_in[0];
    const int*   last_update = (const int*)d_in[1];
    const int*   src         = (const int*)d_in[2];
    const int*   dst         = (const int*)d_in[3];
    const int*   t           = (const int*)d_in[4];
    const float* raw_msg     = (const float*)d_in[5];
    const float* time_w      = (const float*)d_in[6];
    const float* time_b      = (const float*)d_in[7];
    const float* W_ih        = (const float*)d_in[8];
    const float* W_hh        = (const float*)d_in[9];
    const float* b_ih        = (const float*)d_in[10];
    const float* b_hh        = (const float*)d_in[11];

    const int n_nodes  = in_sizes[0] / MEMD;
    const int n_events = in_sizes[2];

    // Workspace layout: ACC(bf16) | cnt | lu | Wb | memB
    short* ACC = (short*)d_ws;
    int*   cnt = (int*)((char*)d_ws + (size_t)n_nodes * ACCD * sizeof(short));
    int*   lu  = cnt + n_nodes;
    bf16x8* Wb = (bf16x8*)(lu + n_nodes);
    short* memB = (short*)(Wb + GI_SLOTS + GH_SLOTS);

    const size_t zero_bytes = (size_t)n_nodes * ACCD * sizeof(short) + 2 * (size_t)n_nodes * sizeof(int);
    (void)hipMemsetAsync(d_ws, 0, zero_bytes, stream);

    tgn_prep_w<<<dim3((GI_SLOTS + GH_SLOTS + 255) / 256), dim3(256), 0, stream>>>(W_ih, W_hh, Wb);

    const int n8 = n_nodes * MEMD / 8;
    tgn_prep_mem<<<dim3((n8 + 255) / 256), dim3(256), 0, stream>>>(memory, memB, n8);

    tgn_scatter<<<dim3((n_events + 3) / 4), dim3(256), 0, stream>>>(
        memB, last_update, src, dst, t, raw_msg, time_w, time_b,
        ACC, cnt, lu, n_events);

    tgn_gru_mfma<<<dim3((n_nodes + 31) / 32), dim3(256), 0, stream>>>(
        memB, ACC, cnt, Wb, b_ih, b_hh, (float*)d_out, n_nodes);

    float* out2 = (float*)d_out + (size_t)n_nodes * MEMD;
    tgn_lu_out<<<dim3((n_nodes + 255) / 256), dim3(256), 0, stream>>>(lu, out2, n_nodes);
}

// Round 6
// 611.778 us; speedup vs baseline: 8.8119x; 1.1409x over previous
//
#include <hip/hip_runtime.h>
#include <cstdint>

// TGN memory update: message scatter-mean (bf16 packed atomics) + MFMA GRU.
// aggr = [mem_self | ACC/cnt]; gi = (cnt>0 ? X @ W_ih^T : 0) + b_ih,
// gh = mem @ W_hh^T + b_hh; GRU epilogue fused, output via LDS-coalesced store.
// Round 6: register-pipelined weight loads (was 1-outstanding-load serialized).

#define MEMD 128
#define ACCD 384
#define MSGD 512

typedef __attribute__((ext_vector_type(8))) short bf16x8;
typedef __attribute__((ext_vector_type(2))) short bf16x2;
typedef __attribute__((ext_vector_type(4))) float f32x4;

static __device__ __forceinline__ short f2bf(float f) {
    uint32_t u = __builtin_bit_cast(uint32_t, f);
    u = (u + 0x7FFFu + ((u >> 16) & 1u)) >> 16;
    return (short)u;
}
static __device__ __forceinline__ float bf2f(short s) {
    return __builtin_bit_cast(float, ((uint32_t)(uint16_t)s) << 16);
}
static __device__ __forceinline__ void atomic_pk_add_bf16(short* p, bf16x2 v) {
    const uint64_t addr = (uint64_t)p;
    asm volatile("global_atomic_pk_add_bf16 %0, %1, off" :: "v"(addr), "v"(v) : "memory");
}

// ---------------- Prep A: memory f32 -> bf16 ----------------
__global__ __launch_bounds__(256) void tgn_prep_mem(
    const float* __restrict__ mem, short* __restrict__ memB, int n8)
{
    const int i = blockIdx.x * 256 + threadIdx.x;
    if (i >= n8) return;
    const float4 a = *reinterpret_cast<const float4*>(mem + (size_t)i * 8);
    const float4 b = *reinterpret_cast<const float4*>(mem + (size_t)i * 8 + 4);
    bf16x8 v;
    v[0] = f2bf(a.x); v[1] = f2bf(a.y); v[2] = f2bf(a.z); v[3] = f2bf(a.w);
    v[4] = f2bf(b.x); v[5] = f2bf(b.y); v[6] = f2bf(b.z); v[7] = f2bf(b.w);
    *reinterpret_cast<bf16x8*>(memB + (size_t)i * 8) = v;
}

// ---------------- Prep B: weights f32 -> bf16 frag-major ----------------
// Wb: gi frags [24 ntile][16 kstep][64 lane], then gh frags [24][4][64].
// Frag (n,ks,lane): j = n*16 + (lane&15), k = ks*32 + (lane>>4)*8 .. +7.
#define GI_SLOTS (24 * 16 * 64)
#define GH_SLOTS (24 * 4 * 64)

__global__ __launch_bounds__(256) void tgn_prep_w(
    const float* __restrict__ W_ih, const float* __restrict__ W_hh,
    bf16x8* __restrict__ Wb)
{
    const int s = blockIdx.x * 256 + threadIdx.x;
    if (s >= GI_SLOTS + GH_SLOTS) return;
    const float* src;
    if (s < GI_SLOTS) {
        const int n = s / (16 * 64), rem = s % (16 * 64);
        const int ks = rem / 64, l = rem % 64;
        const int j = n * 16 + (l & 15), k = ks * 32 + (l >> 4) * 8;
        src = W_ih + (size_t)j * MSGD + k;
    } else {
        const int s2 = s - GI_SLOTS;
        const int n = s2 / (4 * 64), rem = s2 % (4 * 64);
        const int ks = rem / 64, l = rem % 64;
        const int j = n * 16 + (l & 15), k = ks * 32 + (l >> 4) * 8;
        src = W_hh + (size_t)j * MEMD + k;
    }
    bf16x8 v;
    #pragma unroll
    for (int e = 0; e < 8; ++e) v[e] = f2bf(src[e]);
    Wb[s] = v;
}

// ---------------- Phase 1: per-event scatter (packed bf16 atomics) --------
__global__ __launch_bounds__(256) void tgn_scatter(
    const short* __restrict__ memB, const int* __restrict__ last_update,
    const int* __restrict__ src, const int* __restrict__ dst, const int* __restrict__ t,
    const float* __restrict__ raw_msg, const float* __restrict__ time_w,
    const float* __restrict__ time_b,
    short* __restrict__ ACC, int* __restrict__ cnt, int* __restrict__ lu_new,
    int n_events)
{
    const int e = blockIdx.x * 4 + (threadIdx.x >> 6);
    if (e >= n_events) return;
    const int l = threadIdx.x & 63;
    const int j0 = l * 2;

    const int s = src[e];
    const int d = dst[e];
    const int te = t[e];

    const float2 tw = *reinterpret_cast<const float2*>(time_w + j0);
    const float2 tb = *reinterpret_cast<const float2*>(time_b + j0);
    const float dts = (float)(te - last_update[s]);
    const float dtd = (float)(te - last_update[d]);
    bf16x2 tenc_s, tenc_d, rb;
    tenc_s[0] = f2bf(__cosf(fmaf(dts, tw.x, tb.x)));
    tenc_s[1] = f2bf(__cosf(fmaf(dts, tw.y, tb.y)));
    tenc_d[0] = f2bf(__cosf(fmaf(dtd, tw.x, tb.x)));
    tenc_d[1] = f2bf(__cosf(fmaf(dtd, tw.y, tb.y)));

    const bf16x2 ms2 = *reinterpret_cast<const bf16x2*>(memB + (size_t)s * MEMD + j0);
    const bf16x2 md2 = *reinterpret_cast<const bf16x2*>(memB + (size_t)d * MEMD + j0);
    const float2 rw = *reinterpret_cast<const float2*>(raw_msg + (size_t)e * MEMD + j0);
    rb[0] = f2bf(rw.x); rb[1] = f2bf(rw.y);

    short* As = ACC + (size_t)s * ACCD;
    short* Ad = ACC + (size_t)d * ACCD;
    atomic_pk_add_bf16(As + j0, md2);
    atomic_pk_add_bf16(As + 128 + j0, rb);
    atomic_pk_add_bf16(As + 256 + j0, tenc_s);
    atomic_pk_add_bf16(Ad + j0, ms2);
    atomic_pk_add_bf16(Ad + 128 + j0, rb);
    atomic_pk_add_bf16(Ad + 256 + j0, tenc_d);

    if (l == 0) {
        atomicAdd(cnt + s, 1);
        atomicAdd(cnt + d, 1);
        atomicMax(lu_new + s, te);
        atomicMax(lu_new + d, te);
    }
}

// ---------------- Phase 2: MFMA GEMM + GRU ----------------
// 256 threads (4 waves), 32 nodes/block, 32 KB LDS (Xf, reused as Sout).
// Wave w owns N-tiles {w, w+4, ..., w+20}; triples (tpl, tpl+2, tpl+4) give
// (j, j+128, j+256) -> wave-local GRU epilogue.
__global__ __launch_bounds__(256, 4) void tgn_gru_mfma(
    const short* __restrict__ memB, const short* __restrict__ ACC,
    const int* __restrict__ cnt, const bf16x8* __restrict__ Wb,
    const float* __restrict__ b_ih, const float* __restrict__ b_hh,
    float* __restrict__ out, int n_nodes)
{
    __shared__ __align__(16) char smem_raw[32768];
    bf16x8* Xf   = reinterpret_cast<bf16x8*>(smem_raw);   // [2*16*64] frags
    ushort* Xh   = reinterpret_cast<ushort*>(smem_raw);   // u16 view for mv
    float*  Sout = reinterpret_cast<float*>(smem_raw);    // 32x128 f32 after reuse

    const int tid = threadIdx.x;
    const int lane = tid & 63;
    const int node0 = blockIdx.x * 32;

    // ---- stage X tile: issue all loads first (8-deep), then convert ----
    bf16x8 sraw[8];
    float  sinv[8];
    #pragma unroll
    for (int i = 0; i < 8; ++i) {
        const int slot = i * 256 + tid;      // 0..2047
        const int l = slot & 63;
        const int ks = (slot >> 6) & 15;
        const int m = slot >> 10;            // 0..1
        int node = node0 + m * 16 + (l & 15);
        if (node >= n_nodes) node = n_nodes - 1;
        const int kbase = ks * 32 + (l >> 4) * 8;
        if (kbase < 128) {
            sraw[i] = *reinterpret_cast<const bf16x8*>(memB + (size_t)node * MEMD + kbase);
            sinv[i] = -1.0f;                 // marker: no scaling
        } else {
            sraw[i] = *reinterpret_cast<const bf16x8*>(ACC + (size_t)node * ACCD + (kbase - 128));
            const int c = cnt[node];
            sinv[i] = (c > 0) ? 1.0f / (float)c : 0.0f;
        }
    }
    #pragma unroll
    for (int i = 0; i < 8; ++i) {
        const int slot = i * 256 + tid;
        bf16x8 xv = sraw[i];
        if (sinv[i] >= 0.0f) {
            #pragma unroll
            for (int e2 = 0; e2 < 8; ++e2) xv[e2] = f2bf(bf2f(xv[e2]) * sinv[i]);
        }
        Xf[slot] = xv;
    }
    __syncthreads();

    const int wv = __builtin_amdgcn_readfirstlane(tid >> 6); // 0..3
    const int col = lane & 15;
    const int rgrp = lane >> 4;

    f32x4 acc_i[6][2], acc_h[6][2];
    #pragma unroll
    for (int nl = 0; nl < 6; ++nl)
        #pragma unroll
        for (int m = 0; m < 2; ++m) {
            acc_i[nl][m] = (f32x4){0.f, 0.f, 0.f, 0.f};
            acc_h[nl][m] = (f32x4){0.f, 0.f, 0.f, 0.f};
        }

    const bf16x8* __restrict__ Wh = Wb + GI_SLOTS;

    // ---- gh: K=128 (4 ks), register double-buffered B ----
    {
        bf16x8 bc[6], bn[6];
        #pragma unroll
        for (int nl = 0; nl < 6; ++nl) bc[nl] = Wh[((wv + nl * 4) * 4 + 0) * 64 + lane];
        #pragma unroll
        for (int ks = 0; ks < 4; ++ks) {
            if (ks < 3) {
                #pragma unroll
                for (int nl = 0; nl < 6; ++nl) bn[nl] = Wh[((wv + nl * 4) * 4 + ks + 1) * 64 + lane];
            }
            const bf16x8 a0 = Xf[(0 * 16 + ks) * 64 + lane];
            const bf16x8 a1 = Xf[(1 * 16 + ks) * 64 + lane];
            #pragma unroll
            for (int nl = 0; nl < 6; ++nl) {
                acc_h[nl][0] = __builtin_amdgcn_mfma_f32_16x16x32_bf16(a0, bc[nl], acc_h[nl][0], 0, 0, 0);
                acc_h[nl][1] = __builtin_amdgcn_mfma_f32_16x16x32_bf16(a1, bc[nl], acc_h[nl][1], 0, 0, 0);
            }
            #pragma unroll
            for (int nl = 0; nl < 6; ++nl) bc[nl] = bn[nl];
        }
    }

    // ---- gi: K=512 (16 ks), register double-buffered B ----
    {
        bf16x8 bc[6], bn[6];
        #pragma unroll
        for (int nl = 0; nl < 6; ++nl) bc[nl] = Wb[((wv + nl * 4) * 16 + 0) * 64 + lane];
        #pragma unroll
        for (int ks = 0; ks < 16; ++ks) {
            if (ks < 15) {
                #pragma unroll
                for (int nl = 0; nl < 6; ++nl) bn[nl] = Wb[((wv + nl * 4) * 16 + ks + 1) * 64 + lane];
            }
            const bf16x8 a0 = Xf[(0 * 16 + ks) * 64 + lane];
            const bf16x8 a1 = Xf[(1 * 16 + ks) * 64 + lane];
            #pragma unroll
            for (int nl = 0; nl < 6; ++nl) {
                acc_i[nl][0] = __builtin_amdgcn_mfma_f32_16x16x32_bf16(a0, bc[nl], acc_i[nl][0], 0, 0, 0);
                acc_i[nl][1] = __builtin_amdgcn_mfma_f32_16x16x32_bf16(a1, bc[nl], acc_i[nl][1], 0, 0, 0);
            }
            #pragma unroll
            for (int nl = 0; nl < 6; ++nl) bc[nl] = bn[nl];
        }
    }

    // ---- GRU epilogue (wave-local, results to registers) ----
    bool has[2][4];
    #pragma unroll
    for (int m = 0; m < 2; ++m)
        #pragma unroll
        for (int r = 0; r < 4; ++r) {
            int node = node0 + m * 16 + rgrp * 4 + r;
            has[m][r] = (node < n_nodes) && (cnt[node] > 0);
        }

    float rout[2][2][4];
    #pragma unroll
    for (int tpl = 0; tpl < 2; ++tpl) {
        const int jr = (wv + 4 * tpl) * 16 + col; // 0..127
        const float bir = b_ih[jr], biz = b_ih[jr + 128], bin = b_ih[jr + 256];
        const float bhr = b_hh[jr], bhz = b_hh[jr + 128], bhn = b_hh[jr + 256];
        const int ksj = jr >> 5;            // mem part k-step (0..3)
        const int sub = ((jr >> 3) & 3) * 16;
        const int elem = jr & 7;
        #pragma unroll
        for (int m = 0; m < 2; ++m) {
            #pragma unroll
            for (int r = 0; r < 4; ++r) {
                const float gir = (has[m][r] ? acc_i[tpl][m][r] : 0.f) + bir;
                const float giz = (has[m][r] ? acc_i[tpl + 2][m][r] : 0.f) + biz;
                const float gin = (has[m][r] ? acc_i[tpl + 4][m][r] : 0.f) + bin;
                const float ghr = acc_h[tpl][m][r] + bhr;
                const float ghz = acc_h[tpl + 2][m][r] + bhz;
                const float ghn = acc_h[tpl + 4][m][r] + bhn;
                const float rr = __fdividef(1.0f, 1.0f + __expf(-(gir + ghr)));
                const float zz = __fdividef(1.0f, 1.0f + __expf(-(giz + ghz)));
                const float targ = fmaf(rr, ghn, gin);
                const float e2 = __expf(2.0f * targ);
                const float nn = __fdividef(e2 - 1.0f, e2 + 1.0f);
                // mem value from the staged LDS tile (k-steps 0..3 hold mem row)
                const int slot = (m * 16 + ksj) * 64 + sub + (rgrp * 4 + r);
                const float mv = bf2f((short)Xh[slot * 8 + elem]);
                rout[tpl][m][r] = (1.0f - zz) * nn + zz * mv;
            }
        }
    }
    __syncthreads();

    // ---- scatter results to LDS f32 tile [32 nodes][128 cols] ----
    #pragma unroll
    for (int tpl = 0; tpl < 2; ++tpl) {
        const int jr = (wv + 4 * tpl) * 16 + col;
        #pragma unroll
        for (int m = 0; m < 2; ++m)
            #pragma unroll
            for (int r = 0; r < 4; ++r)
                Sout[(m * 16 + rgrp * 4 + r) * MEMD + jr] = rout[tpl][m][r];
    }
    __syncthreads();

    // ---- fully-coalesced float4 write-out ----
    float4* out4 = reinterpret_cast<float4*>(out + (size_t)node0 * MEMD);
    const float4* S4 = reinterpret_cast<const float4*>(Sout);
    if (node0 + 32 <= n_nodes) {
        #pragma unroll
        for (int it = 0; it < 4; ++it)
            out4[it * 256 + tid] = S4[it * 256 + tid];
    } else {
        #pragma unroll
        for (int it = 0; it < 4; ++it) {
            const int idx = it * 256 + tid;             // float4 index in tile
            if (node0 + (idx >> 5) < n_nodes) out4[idx] = S4[idx];
        }
    }
}

// ---------------- Phase 3: last_update -> float out ----------------
__global__ void tgn_lu_out(const int* __restrict__ lu, float* __restrict__ out2, int n_nodes)
{
    const int i = blockIdx.x * blockDim.x + threadIdx.x;
    if (i < n_nodes) out2[i] = (float)lu[i];
}

extern "C" void kernel_launch(void* const* d_in, const int* in_sizes, int n_in,
                              void* d_out, int out_size, void* d_ws, size_t ws_size,
                              hipStream_t stream)
{
    const float* memory      = (const float*)d_in[0];
    const int*   last_update = (const int*)d_in[1];
    const int*   src         = (const int*)d_in[2];
    const int*   dst         = (const int*)d_in[3];
    const int*   t           = (const int*)d_in[4];
    const float* raw_msg     = (const float*)d_in[5];
    const float* time_w      = (const float*)d_in[6];
    const float* time_b      = (const float*)d_in[7];
    const float* W_ih        = (const float*)d_in[8];
    const float* W_hh        = (const float*)d_in[9];
    const float* b_ih        = (const float*)d_in[10];
    const float* b_hh        = (const float*)d_in[11];

    const int n_nodes  = in_sizes[0] / MEMD;
    const int n_events = in_sizes[2];

    // Workspace layout: ACC(bf16) | cnt | lu | Wb | memB
    short* ACC = (short*)d_ws;
    int*   cnt = (int*)((char*)d_ws + (size_t)n_nodes * ACCD * sizeof(short));
    int*   lu  = cnt + n_nodes;
    bf16x8* Wb = (bf16x8*)(lu + n_nodes);
    short* memB = (short*)(Wb + GI_SLOTS + GH_SLOTS);

    const size_t zero_bytes = (size_t)n_nodes * ACCD * sizeof(short) + 2 * (size_t)n_nodes * sizeof(int);
    (void)hipMemsetAsync(d_ws, 0, zero_bytes, stream);

    tgn_prep_w<<<dim3((GI_SLOTS + GH_SLOTS + 255) / 256), dim3(256), 0, stream>>>(W_ih, W_hh, Wb);

    const int n8 = n_nodes * MEMD / 8;
    tgn_prep_mem<<<dim3((n8 + 255) / 256), dim3(256), 0, stream>>>(memory, memB, n8);

    tgn_scatter<<<dim3((n_events + 3) / 4), dim3(256), 0, stream>>>(
        memB, last_update, src, dst, t, raw_msg, time_w, time_b,
        ACC, cnt, lu, n_events);

    tgn_gru_mfma<<<dim3((n_nodes + 31) / 32), dim3(256), 0, stream>>>(
        memB, ACC, cnt, Wb, b_ih, b_hh, (float*)d_out, n_nodes);

    float* out2 = (float*)d_out + (size_t)n_nodes * MEMD;
    tgn_lu_out<<<dim3((n_nodes + 255) / 256), dim3(256), 0, stream>>>(lu, out2, n_nodes);
}